// Round 4
// baseline (209.471 us; speedup 1.0000x reference)
//
#include <hip/hip_runtime.h>

#define NCLS 8
#define NMAPS 4
#define NCH 2048
#define HW 196
#define NB 64
#define NOUT 48   // 32 downconv rows + 8 fc2 rows (cols 2048..4095) + 8 fc1 rows (cols 0..2047)
#define PF 8      // software-pipeline prefetch depth

// ---------------------------------------------------------------------------
// Kernel 0: build transposed combined weight WcT[c][o] (2048 x 48).
// ---------------------------------------------------------------------------
__global__ void build_wct(const float* __restrict__ down_w,
                          const float* __restrict__ fc_w,
                          float* __restrict__ wct) {
    int i = blockIdx.x * 256 + threadIdx.x;   // 48*2048 total
    if (i >= NCH * NOUT) return;
    int o = i >> 11;          // wave-uniform
    int c = i & (NCH - 1);    // coalesced
    float v;
    if (o < 32)      v = down_w[o * NCH + c];
    else if (o < 40) v = fc_w[(o - 32) * (2 * NCH) + NCH + c];
    else             v = fc_w[(o - 40) * (2 * NCH) + c];
    wct[c * NOUT + o] = v;
}

// ---------------------------------------------------------------------------
// Kernel 1: fused 48-row GEMM over x.
//  - lane-packed: t = b*196+p, 64*196 = 49*256 -> 100% lane efficiency
//    (issue floor 20.5 -> 15.7us; batch-boundary waves just split into 2
//    memory segments).
//  - 48 accumulators in ONE pass: x read once from HBM. AGPR demotion (R2:
//    VGPR=40 -> 3 VALU/FMA -> 61.4us, matched measurement) is prevented by
//    __launch_bounds__(256,3): target 3 waves/EU -> VGPR cap ~170, acc stays
//    in arch VGPRs.
//  - manual pipeline + asm barrier blocks loop interchange (R1 failure).
// ---------------------------------------------------------------------------
__global__ __launch_bounds__(256, 3) void conv48(const float* __restrict__ x,
                                                 const float* __restrict__ wct,
                                                 float* __restrict__ part,
                                                 int cpc, int nchunk) {
    const int chunk = blockIdx.x;
    const int t = blockIdx.y * 256 + threadIdx.x;   // 0..12543, all active
    const int b = t / HW;
    const int p = t - b * HW;

    float acc[NOUT];
#pragma unroll
    for (int o = 0; o < NOUT; ++o) acc[o] = 0.f;

    const float* xb = x + ((size_t)b * NCH + (size_t)chunk * cpc) * HW + p;
    const float* wb = wct + (size_t)chunk * cpc * NOUT;

    float xv[PF];
#pragma unroll
    for (int i = 0; i < PF; ++i) xv[i] = xb[i * HW];

    int c0 = 0;
    for (; c0 + 2 * PF <= cpc; c0 += PF) {
        float xn[PF];
#pragma unroll
        for (int i = 0; i < PF; ++i) xn[i] = xb[(c0 + PF + i) * HW];
#pragma unroll
        for (int i = 0; i < PF; ++i) {
            const float* w = wb + (c0 + i) * NOUT;   // uniform -> s_load
#pragma unroll
            for (int o = 0; o < NOUT; ++o)
                acc[o] = fmaf(w[o], xv[i], acc[o]);
        }
#pragma unroll
        for (int i = 0; i < PF; ++i) xv[i] = xn[i];
        __asm__ volatile("" ::: "memory");   // block loop interchange/fission
    }
    // final PF group (already prefetched in xv)
#pragma unroll
    for (int i = 0; i < PF; ++i) {
        const float* w = wb + (c0 + i) * NOUT;
#pragma unroll
        for (int o = 0; o < NOUT; ++o)
            acc[o] = fmaf(w[o], xv[i], acc[o]);
    }

    float* dst = part + ((size_t)(b * nchunk + chunk) * NOUT) * HW + p;
#pragma unroll
    for (int o = 0; o < NOUT; ++o) dst[o * HW] = acc[o];
}

// ---------------------------------------------------------------------------
// Kernel 2: flat chunk-reduction part -> T[b][o][p], all CUs, coalesced.
// ---------------------------------------------------------------------------
__global__ __launch_bounds__(256) void reduce_part(const float* __restrict__ part,
                                                   float* __restrict__ T,
                                                   int nchunk) {
    int idx = blockIdx.x * 256 + threadIdx.x;      // 64*48*196 = 602112
    if (idx >= NB * NOUT * HW) return;
    int b = idx / (NOUT * HW);
    int rem = idx - b * (NOUT * HW);
    const float* src = part + (size_t)b * nchunk * NOUT * HW + rem;
    float s = 0.f;
    for (int ch = 0; ch < nchunk; ++ch)
        s += src[(size_t)ch * NOUT * HW];
    T[idx] = s;
}

// ---------------------------------------------------------------------------
// Kernel 3: per-batch epilogue on the reduced 48x196 slab (2.4 MB total).
// ---------------------------------------------------------------------------
__global__ __launch_bounds__(256) void finish(const float* __restrict__ T,
                                              const float* __restrict__ down_b,
                                              const float* __restrict__ fc_b,
                                              float* __restrict__ out) {
    const int b = blockIdx.x;
    const int tid = threadIdx.x;
    __shared__ float Ts[NOUT * HW];   // 37632 B
    __shared__ float gmpS[32];
    __shared__ float scoreS[8];
    __shared__ float xoS[8];
    __shared__ float salS[HW];
    __shared__ float logitS[8];

    // stage slab into LDS with float4 (2352 float4)
    {
        const float4* src = (const float4*)(T + (size_t)b * NOUT * HW);
        float4* dst = (float4*)Ts;
        for (int i = tid; i < NOUT * HW / 4; i += 256) dst[i] = src[i];
    }
    __syncthreads();

    // global max pool for the 32 downconv rows (+bias commutes past max)
    if (tid < 32) {
        float m = -1e30f;
        for (int p = 0; p < HW; ++p) m = fmaxf(m, Ts[tid * HW + p]);
        gmpS[tid] = m + down_b[tid];
    }
    __syncthreads();

    if (tid < 8)
        scoreS[tid] = 0.25f * (gmpS[4 * tid] + gmpS[4 * tid + 1] +
                               gmpS[4 * tid + 2] + gmpS[4 * tid + 3]);
    __syncthreads();

    // log_softmax over 8 classes -> output 0
    if (tid < 8) {
        float m = -1e30f;
        for (int k = 0; k < 8; ++k) m = fmaxf(m, scoreS[k]);
        float se = 0.f;
        for (int k = 0; k < 8; ++k) se += expf(scoreS[k] - m);
        float xo = scoreS[tid] - m - logf(se);
        xoS[tid] = xo;
        out[b * 8 + tid] = xo;
    }
    __syncthreads();

    // saliency map
    if (tid < HW) {
        float s = 0.f;
#pragma unroll
        for (int k = 0; k < 8; ++k) {
            float bs = down_b[4 * k] + down_b[4 * k + 1] +
                       down_b[4 * k + 2] + down_b[4 * k + 3];
            float rs = Ts[(4 * k) * HW + tid] + Ts[(4 * k + 1) * HW + tid] +
                       Ts[(4 * k + 2) * HW + tid] + Ts[(4 * k + 3) * HW + tid] + bs;
            s += xoS[k] * rs;
        }
        salS[tid] = s * (1.f / 32.f);
    }
    __syncthreads();

    // second logits: fc1 rows (plain mean) + sal-weighted fc2 rows
    if (tid < 8) {
        float t1 = 0.f, t2 = 0.f;
        for (int p = 0; p < HW; ++p) {
            t1 += Ts[(40 + tid) * HW + p];
            t2 += salS[p] * Ts[(32 + tid) * HW + p];
        }
        logitS[tid] = (t1 + t2) * (1.f / 196.f) + fc_b[tid];
    }
    __syncthreads();

    // log_softmax -> output 1
    if (tid < 8) {
        float m = -1e30f;
        for (int k = 0; k < 8; ++k) m = fmaxf(m, logitS[k]);
        float se = 0.f;
        for (int k = 0; k < 8; ++k) se += expf(logitS[k] - m);
        out[NB * 8 + b * 8 + tid] = logitS[tid] - m - logf(se);
    }
}

extern "C" void kernel_launch(void* const* d_in, const int* in_sizes, int n_in,
                              void* d_out, int out_size, void* d_ws, size_t ws_size,
                              hipStream_t stream) {
    const float* x      = (const float*)d_in[0];
    const float* down_w = (const float*)d_in[1];
    const float* down_b = (const float*)d_in[2];
    const float* fc_w   = (const float*)d_in[3];
    const float* fc_b   = (const float*)d_in[4];
    float* out = (float*)d_out;

    float* wct  = (float*)d_ws;                 // 2048*48 = 384 KiB
    float* T    = wct + NCH * NOUT;             // 64*48*196 = 2.3 MiB
    float* part = T + NB * NOUT * HW;           // 64*nchunk*48*196 floats

    // nchunk=16 -> part 38.6 MiB (ws measured 411 MB via poison fill); the
    // grid is then 784 blocks ~= 3 blocks/CU, matching __launch_bounds__(256,3).
    size_t base_bytes = ((size_t)NCH * NOUT + (size_t)NB * NOUT * HW) * 4;
    int nchunk = 16;
    if (ws_size < base_bytes + (size_t)NB * 16 * NOUT * HW * 4) nchunk = 8;
    int cpc = NCH / nchunk;

    build_wct<<<(NCH * NOUT + 255) / 256, 256, 0, stream>>>(down_w, fc_w, wct);
    conv48<<<dim3(nchunk, NB * HW / 256), 256, 0, stream>>>(x, wct, part, cpc, nchunk);
    reduce_part<<<(NB * NOUT * HW + 255) / 256, 256, 0, stream>>>(part, T, nchunk);
    finish<<<NB, 256, 0, stream>>>(T, down_b, fc_b, out);
}

// Round 5
// 202.026 us; speedup vs baseline: 1.0369x; 1.0369x over previous
//
#include <hip/hip_runtime.h>

#define NCH 2048
#define HW 196
#define NB 64
#define NOUT 48    // 32 downconv rows + 8 fc2 rows (cols 2048..4095) + 8 fc1 rows (cols 0..2047)
#define NCHUNK 16
#define CPC (NCH / NCHUNK)   // 128 channels per chunk
#define KSTEPS (CPC / 32)    // 4 MFMA K-steps per chunk
#define KGTOT (NCH / 32)     // 64 global K-steps
#define NT 13                // N-tiles of 16 (208 >= 196 spatial)
#define MT 3                 // M-tiles of 16 (48 outputs)

typedef __attribute__((ext_vector_type(8))) short bf16x8;
typedef __attribute__((ext_vector_type(4))) float f32x4;

// fp32 -> bf16, round-to-nearest-even (bit trick, no header-struct dependency)
__device__ __forceinline__ short f2bf(float f) {
    unsigned int u = __float_as_uint(f);
    u = u + 0x7fffu + ((u >> 16) & 1u);
    return (short)(u >> 16);
}

// ---------------------------------------------------------------------------
// Kernel 0: build A-fragments (weights) pre-swizzled to MFMA A-operand order.
// A[m][k] for 16x16x32 bf16: lane l holds m = l&15, k = (l>>4)*8 + j, j=0..7
// (m120-verified layout). Stored as [kg][mt][lane] x 8 bf16 -> each lane in
// conv_mfma loads its fragment with ONE global_load_dwordx4.
// ---------------------------------------------------------------------------
__global__ void build_afrag(const float* __restrict__ down_w,
                            const float* __restrict__ fc_w,
                            bf16x8* __restrict__ afrag) {
    int t = blockIdx.x * 256 + threadIdx.x;        // 64*3*64 = 12288
    if (t >= KGTOT * MT * 64) return;
    int lane = t & 63;
    int frag = t >> 6;
    int mt = frag % MT;
    int kg = frag / MT;
    int o = mt * 16 + (lane & 15);
    int cbase = kg * 32 + (lane >> 4) * 8;
    bf16x8 v;
#pragma unroll
    for (int j = 0; j < 8; ++j) {
        int c = cbase + j;
        float w;
        if (o < 32)      w = down_w[o * NCH + c];
        else if (o < 40) w = fc_w[(o - 32) * (2 * NCH) + NCH + c];
        else             w = fc_w[(o - 40) * (2 * NCH) + c];
        v[j] = f2bf(w);
    }
    afrag[frag * 64 + lane] = v;
}

// ---------------------------------------------------------------------------
// Kernel 1: MFMA GEMM. Per block (chunk, batch): D[48 x 208] partial over 128
// channels. 4 waves split N-tiles (wave w owns nt = w, w+4, w+8, w+12).
// B-frag (x): lane l needs x[c0 + (l>>4)*8 + j][p0 + (l&15)] -- loaded fp32
// (4x64B segments/inst, full line use), converted to bf16 in-reg.
// R1-R4 postmortem: VALU path is weight-s_load-stall-bound at ~60us no matter
// the accumulator layout; MFMA moves weights to a 16B/lane frag load.
// ---------------------------------------------------------------------------
__global__ __launch_bounds__(256, 4) void conv_mfma(const float* __restrict__ x,
                                                    const bf16x8* __restrict__ afrag,
                                                    float* __restrict__ part) {
    const int chunk = blockIdx.x;
    const int b = blockIdx.y;
    const int wave = threadIdx.x >> 6;
    const int lane = threadIdx.x & 63;
    const int nsub = lane & 15;
    const int kq = lane >> 4;

    f32x4 acc[4][MT];
#pragma unroll
    for (int i = 0; i < 4; ++i)
#pragma unroll
        for (int m = 0; m < MT; ++m)
            acc[i][m] = (f32x4){0.f, 0.f, 0.f, 0.f};

    // spatial index per owned N-tile, clamped in-bounds (garbage cols never stored)
    int pidx[4];
#pragma unroll
    for (int i = 0; i < 4; ++i) {
        int p = (wave + 4 * i) * 16 + nsub;
        pidx[i] = (p < HW) ? p : (HW - 1);
    }

    const float* xb = x + ((size_t)b * NCH + (size_t)chunk * CPC) * HW;

    for (int ks = 0; ks < KSTEPS; ++ks) {
        const int kg = chunk * KSTEPS + ks;
        bf16x8 a0 = afrag[(kg * MT + 0) * 64 + lane];
        bf16x8 a1 = afrag[(kg * MT + 1) * 64 + lane];
        bf16x8 a2 = afrag[(kg * MT + 2) * 64 + lane];
        const float* xk = xb + (ks * 32 + kq * 8) * HW;
#pragma unroll
        for (int i = 0; i < 4; ++i) {
            float f[8];
#pragma unroll
            for (int j = 0; j < 8; ++j) f[j] = xk[j * HW + pidx[i]];
            bf16x8 bv;
#pragma unroll
            for (int j = 0; j < 8; ++j) bv[j] = f2bf(f[j]);
            acc[i][0] = __builtin_amdgcn_mfma_f32_16x16x32_bf16(a0, bv, acc[i][0], 0, 0, 0);
            acc[i][1] = __builtin_amdgcn_mfma_f32_16x16x32_bf16(a1, bv, acc[i][1], 0, 0, 0);
            acc[i][2] = __builtin_amdgcn_mfma_f32_16x16x32_bf16(a2, bv, acc[i][2], 0, 0, 0);
        }
    }

    // C/D layout (m89-verified): col = lane&15 (=p), row = (lane>>4)*4 + reg (=o)
    float* dst = part + ((size_t)(b * NCHUNK + chunk) * NOUT) * HW;
#pragma unroll
    for (int i = 0; i < 4; ++i) {
        int nt = wave + 4 * i;
        int p = nt * 16 + nsub;
        if (nt < NT && p < HW) {
#pragma unroll
            for (int m = 0; m < MT; ++m)
#pragma unroll
                for (int r = 0; r < 4; ++r)
                    dst[(m * 16 + kq * 4 + r) * HW + p] = acc[i][m][r];
        }
    }
}

// ---------------------------------------------------------------------------
// Kernel 2: flat chunk-reduction part -> T[b][o][p], all CUs, coalesced.
// ---------------------------------------------------------------------------
__global__ __launch_bounds__(256) void reduce_part(const float* __restrict__ part,
                                                   float* __restrict__ T) {
    int idx = blockIdx.x * 256 + threadIdx.x;      // 64*48*196 = 602112
    if (idx >= NB * NOUT * HW) return;
    int b = idx / (NOUT * HW);
    int rem = idx - b * (NOUT * HW);
    const float* src = part + (size_t)b * NCHUNK * NOUT * HW + rem;
    float s = 0.f;
#pragma unroll
    for (int ch = 0; ch < NCHUNK; ++ch)
        s += src[(size_t)ch * NOUT * HW];
    T[idx] = s;
}

// ---------------------------------------------------------------------------
// Kernel 3: per-batch epilogue on the reduced 48x196 slab.
// ---------------------------------------------------------------------------
__global__ __launch_bounds__(256) void finish(const float* __restrict__ T,
                                              const float* __restrict__ down_b,
                                              const float* __restrict__ fc_b,
                                              float* __restrict__ out) {
    const int b = blockIdx.x;
    const int tid = threadIdx.x;
    __shared__ float Ts[NOUT * HW];
    __shared__ float gmpS[32];
    __shared__ float scoreS[8];
    __shared__ float xoS[8];
    __shared__ float salS[HW];
    __shared__ float logitS[8];

    {
        const float4* src = (const float4*)(T + (size_t)b * NOUT * HW);
        float4* dst = (float4*)Ts;
        for (int i = tid; i < NOUT * HW / 4; i += 256) dst[i] = src[i];
    }
    __syncthreads();

    if (tid < 32) {
        float m = -1e30f;
        for (int p = 0; p < HW; ++p) m = fmaxf(m, Ts[tid * HW + p]);
        gmpS[tid] = m + down_b[tid];
    }
    __syncthreads();

    if (tid < 8)
        scoreS[tid] = 0.25f * (gmpS[4 * tid] + gmpS[4 * tid + 1] +
                               gmpS[4 * tid + 2] + gmpS[4 * tid + 3]);
    __syncthreads();

    if (tid < 8) {
        float m = -1e30f;
        for (int k = 0; k < 8; ++k) m = fmaxf(m, scoreS[k]);
        float se = 0.f;
        for (int k = 0; k < 8; ++k) se += expf(scoreS[k] - m);
        float xo = scoreS[tid] - m - logf(se);
        xoS[tid] = xo;
        out[b * 8 + tid] = xo;
    }
    __syncthreads();

    if (tid < HW) {
        float s = 0.f;
#pragma unroll
        for (int k = 0; k < 8; ++k) {
            float bs = down_b[4 * k] + down_b[4 * k + 1] +
                       down_b[4 * k + 2] + down_b[4 * k + 3];
            float rs = Ts[(4 * k) * HW + tid] + Ts[(4 * k + 1) * HW + tid] +
                       Ts[(4 * k + 2) * HW + tid] + Ts[(4 * k + 3) * HW + tid] + bs;
            s += xoS[k] * rs;
        }
        salS[tid] = s * (1.f / 32.f);
    }
    __syncthreads();

    if (tid < 8) {
        float t1 = 0.f, t2 = 0.f;
        for (int p = 0; p < HW; ++p) {
            t1 += Ts[(40 + tid) * HW + p];
            t2 += salS[p] * Ts[(32 + tid) * HW + p];
        }
        logitS[tid] = (t1 + t2) * (1.f / 196.f) + fc_b[tid];
    }
    __syncthreads();

    if (tid < 8) {
        float m = -1e30f;
        for (int k = 0; k < 8; ++k) m = fmaxf(m, logitS[k]);
        float se = 0.f;
        for (int k = 0; k < 8; ++k) se += expf(logitS[k] - m);
        out[NB * 8 + b * 8 + tid] = logitS[tid] - m - logf(se);
    }
}

extern "C" void kernel_launch(void* const* d_in, const int* in_sizes, int n_in,
                              void* d_out, int out_size, void* d_ws, size_t ws_size,
                              hipStream_t stream) {
    const float* x      = (const float*)d_in[0];
    const float* down_w = (const float*)d_in[1];
    const float* down_b = (const float*)d_in[2];
    const float* fc_w   = (const float*)d_in[3];
    const float* fc_b   = (const float*)d_in[4];
    float* out = (float*)d_out;

    bf16x8* afrag = (bf16x8*)d_ws;                                   // 192 KiB
    float* T    = (float*)((char*)d_ws + (size_t)KGTOT * MT * 64 * 16);  // 2.3 MiB
    float* part = T + (size_t)NB * NOUT * HW;                        // 36.7 MiB

    build_afrag<<<(KGTOT * MT * 64 + 255) / 256, 256, 0, stream>>>(down_w, fc_w, afrag);
    conv_mfma<<<dim3(NCHUNK, NB), 256, 0, stream>>>(x, afrag, part);
    reduce_part<<<(NB * NOUT * HW + 255) / 256, 256, 0, stream>>>(part, T);
    finish<<<NB, 256, 0, stream>>>(T, down_b, fc_b, out);
}

// Round 6
// 186.203 us; speedup vs baseline: 1.1250x; 1.0850x over previous
//
#include <hip/hip_runtime.h>

#define NCH 2048
#define HW 196
#define NB 64
#define NOUT 48    // 32 downconv rows + 8 fc2 rows (cols 2048..4095) + 8 fc1 rows (cols 0..2047)
#define NCHUNK 8
#define CPC (NCH / NCHUNK)     // 256 channels per block
#define KS_PER_BLK (CPC / 32)  // 8 K-steps of 32 channels
#define KGTOT (NCH / 32)       // 64 global K-steps
#define NT 13                  // N-tiles of 16 (208 >= 196)
#define MT 3                   // M-tiles of 16 (48 outputs)
#define TILE_F (32 * HW)       // 6272 floats per K-step tile (25088 B, contiguous in x!)
#define TILE_V4 (TILE_F / 4)   // 1568 float4

typedef __attribute__((ext_vector_type(8))) short bf16x8;
typedef __attribute__((ext_vector_type(4))) float f32x4;

__device__ __forceinline__ short f2bf(float f) {   // fp32->bf16 RNE
    unsigned int u = __float_as_uint(f);
    u = u + 0x7fffu + ((u >> 16) & 1u);
    return (short)(u >> 16);
}

// ---------------------------------------------------------------------------
// Kernel 0: weights pre-swizzled to MFMA A-fragment order (R5-verified).
// ---------------------------------------------------------------------------
__global__ void build_afrag(const float* __restrict__ down_w,
                            const float* __restrict__ fc_w,
                            bf16x8* __restrict__ afrag) {
    int t = blockIdx.x * 256 + threadIdx.x;        // 64*3*64 = 12288
    if (t >= KGTOT * MT * 64) return;
    int lane = t & 63;
    int frag = t >> 6;
    int mt = frag % MT;
    int kg = frag / MT;
    int o = mt * 16 + (lane & 15);
    int cbase = kg * 32 + (lane >> 4) * 8;
    bf16x8 v;
#pragma unroll
    for (int j = 0; j < 8; ++j) {
        int c = cbase + j;
        float w;
        if (o < 32)      w = down_w[o * NCH + c];
        else if (o < 40) w = fc_w[(o - 32) * (2 * NCH) + NCH + c];
        else             w = fc_w[(o - 40) * (2 * NCH) + c];
        v[j] = f2bf(w);
    }
    afrag[frag * 64 + lane] = v;
}

// ---------------------------------------------------------------------------
// Kernel 1: MFMA GEMM, LDS-staged (canonical double-buffer).
// R5 postmortem: per-lane 4B gathers + VGPR starvation -> latency-bound 63us
// (MfmaUtil 1.9%, VALUBusy 6%, 24% HBM). Fix: each 32-ch K-step tile is a
// CONTIGUOUS 25088B global region -> global_load_lds width=16 DMA (no VGPR
// dest, unlimited MLP), fragments via ds_read_b32 from LDS.
// part stored blocked [b][chunk][nt][o][16] for dense full-line writes (R5
// strided layout showed 1.4x write amplification).
// ---------------------------------------------------------------------------
__global__ __launch_bounds__(256) void conv_mfma(const float* __restrict__ x,
                                                 const bf16x8* __restrict__ afrag,
                                                 float* __restrict__ part) {
    __shared__ float ldsx[2][TILE_F];   // 2 x 25088 B
    const int chunk = blockIdx.x;
    const int b = blockIdx.y;
    const int tid = threadIdx.x;
    const int wave = tid >> 6;
    const int lane = tid & 63;
    const int nsub = lane & 15;
    const int kq = lane >> 4;

    f32x4 acc[4][MT];
#pragma unroll
    for (int i = 0; i < 4; ++i)
#pragma unroll
        for (int m = 0; m < MT; ++m)
            acc[i][m] = (f32x4){0.f, 0.f, 0.f, 0.f};

    int pidx[4];
#pragma unroll
    for (int i = 0; i < 4; ++i) {
        int p = (wave + 4 * i) * 16 + nsub;
        pidx[i] = (p < HW) ? p : (HW - 1);   // clamp; garbage never stored
    }

    const float* xtile0 = x + ((size_t)b * NCH + (size_t)chunk * CPC) * HW;

    // async stage of one K-step tile into LDS buffer bb (wave-uniform base +
    // lane*16 per the global_load_lds contract; tile is contiguous in global)
    auto stage = [&](int ks, int bb) {
        const float* g = xtile0 + (size_t)ks * TILE_F;
#pragma unroll
        for (int r = 0; r < 7; ++r) {              // ceil(1568/256)
            int q = r * 256 + tid;
            if (q < TILE_V4) {
                __builtin_amdgcn_global_load_lds(
                    (const __attribute__((address_space(1))) unsigned int*)(g + (size_t)q * 4),
                    (__attribute__((address_space(3))) unsigned int*)(&ldsx[bb][(r * 256 + wave * 64) * 4]),
                    16, 0, 0);
            }
        }
    };

    stage(0, 0);

    for (int ks = 0; ks < KS_PER_BLK; ++ks) {
        __syncthreads();                  // barrier drains vmcnt -> tile ks visible
        if (ks + 1 < KS_PER_BLK) stage(ks + 1, (ks + 1) & 1);

        const int kg = chunk * KS_PER_BLK + ks;
        bf16x8 a0 = afrag[(kg * MT + 0) * 64 + lane];
        bf16x8 a1 = afrag[(kg * MT + 1) * 64 + lane];
        bf16x8 a2 = afrag[(kg * MT + 2) * 64 + lane];

        const float* base = &ldsx[ks & 1][kq * 8 * HW];
#pragma unroll
        for (int i = 0; i < 4; ++i) {
            const float* bp = base + pidx[i];
            float f[8];
#pragma unroll
            for (int j = 0; j < 8; ++j) f[j] = bp[j * HW];   // ds_read_b32 + imm
            bf16x8 bv;
#pragma unroll
            for (int j = 0; j < 8; ++j) bv[j] = f2bf(f[j]);
            acc[i][0] = __builtin_amdgcn_mfma_f32_16x16x32_bf16(a0, bv, acc[i][0], 0, 0, 0);
            acc[i][1] = __builtin_amdgcn_mfma_f32_16x16x32_bf16(a1, bv, acc[i][1], 0, 0, 0);
            acc[i][2] = __builtin_amdgcn_mfma_f32_16x16x32_bf16(a2, bv, acc[i][2], 0, 0, 0);
        }
    }

    // blocked store: part[b][chunk][nt][o][16], o = m*16 + kq*4 + r
    // (C/D layout m89-verified: col=nsub=p, row=kq*4+r=o within the 16-tile)
    float* pb = part + (size_t)(b * NCHUNK + chunk) * (NT * NOUT * 16);
#pragma unroll
    for (int i = 0; i < 4; ++i) {
        int nt = wave + 4 * i;
        if (nt < NT) {
            float* d = pb + nt * (NOUT * 16) + kq * 64 + nsub;
#pragma unroll
            for (int m = 0; m < MT; ++m)
#pragma unroll
                for (int r = 0; r < 4; ++r)
                    d[m * 256 + r * 16] = acc[i][m][r];
        }
    }
}

// ---------------------------------------------------------------------------
// Kernel 2: chunk-reduction from blocked part -> T[b][o][p].
// ---------------------------------------------------------------------------
__global__ __launch_bounds__(256) void reduce_part(const float* __restrict__ part,
                                                   float* __restrict__ T) {
    int idx = blockIdx.x * 256 + threadIdx.x;      // 64*48*196 = 602112
    if (idx >= NB * NOUT * HW) return;
    int b = idx / (NOUT * HW);
    int rem = idx - b * (NOUT * HW);
    int o = rem / HW;
    int p = rem - o * HW;
    int nt = p >> 4, ns = p & 15;
    const float* src = part + (size_t)b * NCHUNK * NT * NOUT * 16
                     + nt * (NOUT * 16) + o * 16 + ns;
    float s = 0.f;
#pragma unroll
    for (int ch = 0; ch < NCHUNK; ++ch)
        s += src[(size_t)ch * NT * NOUT * 16];
    T[idx] = s;
}

// ---------------------------------------------------------------------------
// Kernel 3: per-batch epilogue on the reduced 48x196 slab.
// ---------------------------------------------------------------------------
__global__ __launch_bounds__(256) void finish(const float* __restrict__ T,
                                              const float* __restrict__ down_b,
                                              const float* __restrict__ fc_b,
                                              float* __restrict__ out) {
    const int b = blockIdx.x;
    const int tid = threadIdx.x;
    __shared__ float Ts[NOUT * HW];
    __shared__ float gmpS[32];
    __shared__ float scoreS[8];
    __shared__ float xoS[8];
    __shared__ float salS[HW];
    __shared__ float logitS[8];

    {
        const float4* src = (const float4*)(T + (size_t)b * NOUT * HW);
        float4* dst = (float4*)Ts;
        for (int i = tid; i < NOUT * HW / 4; i += 256) dst[i] = src[i];
    }
    __syncthreads();

    if (tid < 32) {
        float m = -1e30f;
        for (int p = 0; p < HW; ++p) m = fmaxf(m, Ts[tid * HW + p]);
        gmpS[tid] = m + down_b[tid];
    }
    __syncthreads();

    if (tid < 8)
        scoreS[tid] = 0.25f * (gmpS[4 * tid] + gmpS[4 * tid + 1] +
                               gmpS[4 * tid + 2] + gmpS[4 * tid + 3]);
    __syncthreads();

    if (tid < 8) {
        float m = -1e30f;
        for (int k = 0; k < 8; ++k) m = fmaxf(m, scoreS[k]);
        float se = 0.f;
        for (int k = 0; k < 8; ++k) se += expf(scoreS[k] - m);
        float xo = scoreS[tid] - m - logf(se);
        xoS[tid] = xo;
        out[b * 8 + tid] = xo;
    }
    __syncthreads();

    if (tid < HW) {
        float s = 0.f;
#pragma unroll
        for (int k = 0; k < 8; ++k) {
            float bs = down_b[4 * k] + down_b[4 * k + 1] +
                       down_b[4 * k + 2] + down_b[4 * k + 3];
            float rs = Ts[(4 * k) * HW + tid] + Ts[(4 * k + 1) * HW + tid] +
                       Ts[(4 * k + 2) * HW + tid] + Ts[(4 * k + 3) * HW + tid] + bs;
            s += xoS[k] * rs;
        }
        salS[tid] = s * (1.f / 32.f);
    }
    __syncthreads();

    if (tid < 8) {
        float t1 = 0.f, t2 = 0.f;
        for (int p = 0; p < HW; ++p) {
            t1 += Ts[(40 + tid) * HW + p];
            t2 += salS[p] * Ts[(32 + tid) * HW + p];
        }
        logitS[tid] = (t1 + t2) * (1.f / 196.f) + fc_b[tid];
    }
    __syncthreads();

    if (tid < 8) {
        float m = -1e30f;
        for (int k = 0; k < 8; ++k) m = fmaxf(m, logitS[k]);
        float se = 0.f;
        for (int k = 0; k < 8; ++k) se += expf(logitS[k] - m);
        out[NB * 8 + b * 8 + tid] = logitS[tid] - m - logf(se);
    }
}

extern "C" void kernel_launch(void* const* d_in, const int* in_sizes, int n_in,
                              void* d_out, int out_size, void* d_ws, size_t ws_size,
                              hipStream_t stream) {
    const float* x      = (const float*)d_in[0];
    const float* down_w = (const float*)d_in[1];
    const float* down_b = (const float*)d_in[2];
    const float* fc_w   = (const float*)d_in[3];
    const float* fc_b   = (const float*)d_in[4];
    float* out = (float*)d_out;

    bf16x8* afrag = (bf16x8*)d_ws;                                       // 192 KiB
    float* T    = (float*)((char*)d_ws + (size_t)KGTOT * MT * 64 * 16);  // 2.3 MiB
    float* part = T + (size_t)NB * NOUT * HW;                            // 20.4 MiB

    build_afrag<<<(KGTOT * MT * 64 + 255) / 256, 256, 0, stream>>>(down_w, fc_w, afrag);
    conv_mfma<<<dim3(NCHUNK, NB), 256, 0, stream>>>(x, afrag, part);
    reduce_part<<<(NB * NOUT * HW + 255) / 256, 256, 0, stream>>>(part, T);
    finish<<<NB, 256, 0, stream>>>(T, down_b, fc_b, out);
}

// Round 7
// 183.339 us; speedup vs baseline: 1.1425x; 1.0156x over previous
//
#include <hip/hip_runtime.h>

#define NCH 2048
#define HW 196
#define NB 64
#define NOUT 48    // 32 downconv rows + 8 fc2 rows (cols 2048..4095) + 8 fc1 rows (cols 0..2047)
#define NCHUNK 8
#define CPC (NCH / NCHUNK)     // 256 channels per block
#define KS_PER_BLK (CPC / 32)  // 8 K-steps of 32 channels
#define KGTOT (NCH / 32)       // 64 global K-steps
#define NT 13                  // N-tiles of 16 (208 >= 196)
#define MT 3                   // M-tiles of 16 (48 outputs)
#define TILE_F (32 * HW)       // 6272 floats per K-step tile (25088 B, contiguous in x)
#define TILE_V4 (TILE_F / 4)   // 1568 float4
#define SLAB (NT * NOUT * 16)  // 9984 floats per (b,chunk) blocked slab
#define SLAB4 (SLAB / 4)       // 2496 float4

typedef __attribute__((ext_vector_type(8))) short bf16x8;
typedef __attribute__((ext_vector_type(4))) float f32x4;
typedef __attribute__((ext_vector_type(4))) int i32x4;

__device__ __forceinline__ short f2bf(float f) {   // fp32->bf16 RNE (weights)
    unsigned int u = __float_as_uint(f);
    u = u + 0x7fffu + ((u >> 16) & 1u);
    return (short)(u >> 16);
}

// ---------------------------------------------------------------------------
// Kernel 0: weights pre-swizzled to MFMA A-fragment order (R5/R6-verified).
// ---------------------------------------------------------------------------
__global__ void build_afrag(const float* __restrict__ down_w,
                            const float* __restrict__ fc_w,
                            bf16x8* __restrict__ afrag) {
    int t = blockIdx.x * 256 + threadIdx.x;        // 64*3*64 = 12288
    if (t >= KGTOT * MT * 64) return;
    int lane = t & 63;
    int frag = t >> 6;
    int mt = frag % MT;
    int kg = frag / MT;
    int o = mt * 16 + (lane & 15);
    int cbase = kg * 32 + (lane >> 4) * 8;
    bf16x8 v;
#pragma unroll
    for (int j = 0; j < 8; ++j) {
        int c = cbase + j;
        float w;
        if (o < 32)      w = down_w[o * NCH + c];
        else if (o < 40) w = fc_w[(o - 32) * (2 * NCH) + NCH + c];
        else             w = fc_w[(o - 40) * (2 * NCH) + c];
        v[j] = f2bf(w);
    }
    afrag[frag * 64 + lane] = v;
}

// ---------------------------------------------------------------------------
// Kernel 1: MFMA GEMM, LDS-staged double-buffer (R6 structure, proven).
// R7 change: bf16 convert via +0x8000 round-half-up + v_perm_b32 byte pack
// (3 insts / 2 elems instead of ~4/elem RNE bit-trick) -- the cvt was ~40%
// of the compute-phase VALU.
// ---------------------------------------------------------------------------
__global__ __launch_bounds__(256) void conv_mfma(const float* __restrict__ x,
                                                 const bf16x8* __restrict__ afrag,
                                                 float* __restrict__ part) {
    __shared__ float ldsx[2][TILE_F];   // 2 x 25088 B
    const int chunk = blockIdx.x;
    const int b = blockIdx.y;
    const int tid = threadIdx.x;
    const int wave = tid >> 6;
    const int lane = tid & 63;
    const int nsub = lane & 15;
    const int kq = lane >> 4;

    f32x4 acc[4][MT];
#pragma unroll
    for (int i = 0; i < 4; ++i)
#pragma unroll
        for (int m = 0; m < MT; ++m)
            acc[i][m] = (f32x4){0.f, 0.f, 0.f, 0.f};

    int pidx[4];
#pragma unroll
    for (int i = 0; i < 4; ++i) {
        int p = (wave + 4 * i) * 16 + nsub;
        pidx[i] = (p < HW) ? p : (HW - 1);   // clamp; junk cols ignored downstream
    }

    const float* xtile0 = x + ((size_t)b * NCH + (size_t)chunk * CPC) * HW;

    auto stage = [&](int ks, int bb) {
        const float* g = xtile0 + (size_t)ks * TILE_F;
#pragma unroll
        for (int r = 0; r < 7; ++r) {              // ceil(1568/256)
            int q = r * 256 + tid;
            if (q < TILE_V4) {
                __builtin_amdgcn_global_load_lds(
                    (const __attribute__((address_space(1))) unsigned int*)(g + (size_t)q * 4),
                    (__attribute__((address_space(3))) unsigned int*)(&ldsx[bb][(r * 256 + wave * 64) * 4]),
                    16, 0, 0);
            }
        }
    };

    stage(0, 0);

    for (int ks = 0; ks < KS_PER_BLK; ++ks) {
        __syncthreads();                  // barrier drains vmcnt -> tile ks visible
        if (ks + 1 < KS_PER_BLK) stage(ks + 1, (ks + 1) & 1);

        const int kg = chunk * KS_PER_BLK + ks;
        bf16x8 a0 = afrag[(kg * MT + 0) * 64 + lane];
        bf16x8 a1 = afrag[(kg * MT + 1) * 64 + lane];
        bf16x8 a2 = afrag[(kg * MT + 2) * 64 + lane];

        const float* base = &ldsx[ks & 1][kq * 8 * HW];
#pragma unroll
        for (int i = 0; i < 4; ++i) {
            const float* bp = base + pidx[i];
            unsigned int u[8];
#pragma unroll
            for (int j = 0; j < 8; ++j)
                u[j] = __float_as_uint(bp[j * HW]) + 0x8000u;  // round-half-up
            i32x4 bi;
            bi[0] = (int)__builtin_amdgcn_perm(u[1], u[0], 0x07060302u);
            bi[1] = (int)__builtin_amdgcn_perm(u[3], u[2], 0x07060302u);
            bi[2] = (int)__builtin_amdgcn_perm(u[5], u[4], 0x07060302u);
            bi[3] = (int)__builtin_amdgcn_perm(u[7], u[6], 0x07060302u);
            bf16x8 bv = __builtin_bit_cast(bf16x8, bi);
            acc[i][0] = __builtin_amdgcn_mfma_f32_16x16x32_bf16(a0, bv, acc[i][0], 0, 0, 0);
            acc[i][1] = __builtin_amdgcn_mfma_f32_16x16x32_bf16(a1, bv, acc[i][1], 0, 0, 0);
            acc[i][2] = __builtin_amdgcn_mfma_f32_16x16x32_bf16(a2, bv, acc[i][2], 0, 0, 0);
        }
    }

    // blocked store: part[b][chunk][nt][o][16], o = m*16 + kq*4 + r
    float* pb = part + (size_t)(b * NCHUNK + chunk) * SLAB;
#pragma unroll
    for (int i = 0; i < 4; ++i) {
        int nt = wave + 4 * i;
        if (nt < NT) {
            float* d = pb + nt * (NOUT * 16) + kq * 64 + nsub;
#pragma unroll
            for (int m = 0; m < MT; ++m)
#pragma unroll
                for (int r = 0; r < 4; ++r)
                    d[m * 256 + r * 16] = acc[i][m][r];
        }
    }
}

// ---------------------------------------------------------------------------
// Kernel 2: per-batch fused chunk-reduce + epilogue.
// Reduces the 8 blocked slabs of this batch with float4 (coalesced, part is
// L2/L3-resident), scatters into Ts[o][p] in LDS, then the epilogue chain.
// Replaces R6's reduce_part + finish (one less launch + no T round-trip).
// ---------------------------------------------------------------------------
__global__ __launch_bounds__(256) void finish(const float* __restrict__ part,
                                              const float* __restrict__ down_b,
                                              const float* __restrict__ fc_b,
                                              float* __restrict__ out) {
    const int b = blockIdx.x;
    const int tid = threadIdx.x;
    __shared__ float Ts[NOUT * HW];
    __shared__ float gmpS[32];
    __shared__ float scoreS[8];
    __shared__ float xoS[8];
    __shared__ float salS[HW];
    __shared__ float logitS[8];

    {
        const float4* base = (const float4*)(part + (size_t)b * NCHUNK * SLAB);
        for (int i4 = tid; i4 < SLAB4; i4 += 256) {
            float4 s = base[i4];
#pragma unroll
            for (int ch = 1; ch < NCHUNK; ++ch) {
                float4 v = base[(size_t)ch * SLAB4 + i4];
                s.x += v.x; s.y += v.y; s.z += v.z; s.w += v.w;
            }
            int nt = i4 / 192;               // NOUT*16/4
            int rem = i4 - nt * 192;
            int o = rem >> 2, ns4 = rem & 3;
            int p = nt * 16 + ns4 * 4;
            float vv[4] = {s.x, s.y, s.z, s.w};
#pragma unroll
            for (int q = 0; q < 4; ++q)
                if (p + q < HW) Ts[o * HW + p + q] = vv[q];
        }
    }
    __syncthreads();

    if (tid < 32) {
        float m = -1e30f;
        for (int p = 0; p < HW; ++p) m = fmaxf(m, Ts[tid * HW + p]);
        gmpS[tid] = m + down_b[tid];
    }
    __syncthreads();

    if (tid < 8)
        scoreS[tid] = 0.25f * (gmpS[4 * tid] + gmpS[4 * tid + 1] +
                               gmpS[4 * tid + 2] + gmpS[4 * tid + 3]);
    __syncthreads();

    if (tid < 8) {
        float m = -1e30f;
        for (int k = 0; k < 8; ++k) m = fmaxf(m, scoreS[k]);
        float se = 0.f;
        for (int k = 0; k < 8; ++k) se += expf(scoreS[k] - m);
        float xo = scoreS[tid] - m - logf(se);
        xoS[tid] = xo;
        out[b * 8 + tid] = xo;
    }
    __syncthreads();

    if (tid < HW) {
        float s = 0.f;
#pragma unroll
        for (int k = 0; k < 8; ++k) {
            float bs = down_b[4 * k] + down_b[4 * k + 1] +
                       down_b[4 * k + 2] + down_b[4 * k + 3];
            float rs = Ts[(4 * k) * HW + tid] + Ts[(4 * k + 1) * HW + tid] +
                       Ts[(4 * k + 2) * HW + tid] + Ts[(4 * k + 3) * HW + tid] + bs;
            s += xoS[k] * rs;
        }
        salS[tid] = s * (1.f / 32.f);
    }
    __syncthreads();

    if (tid < 8) {
        float t1 = 0.f, t2 = 0.f;
        for (int p = 0; p < HW; ++p) {
            t1 += Ts[(40 + tid) * HW + p];
            t2 += salS[p] * Ts[(32 + tid) * HW + p];
        }
        logitS[tid] = (t1 + t2) * (1.f / 196.f) + fc_b[tid];
    }
    __syncthreads();

    if (tid < 8) {
        float m = -1e30f;
        for (int k = 0; k < 8; ++k) m = fmaxf(m, logitS[k]);
        float se = 0.f;
        for (int k = 0; k < 8; ++k) se += expf(logitS[k] - m);
        out[NB * 8 + b * 8 + tid] = logitS[tid] - m - logf(se);
    }
}

extern "C" void kernel_launch(void* const* d_in, const int* in_sizes, int n_in,
                              void* d_out, int out_size, void* d_ws, size_t ws_size,
                              hipStream_t stream) {
    const float* x      = (const float*)d_in[0];
    const float* down_w = (const float*)d_in[1];
    const float* down_b = (const float*)d_in[2];
    const float* fc_w   = (const float*)d_in[3];
    const float* fc_b   = (const float*)d_in[4];
    float* out = (float*)d_out;

    bf16x8* afrag = (bf16x8*)d_ws;                                        // 192 KiB
    float* part = (float*)((char*)d_ws + (size_t)KGTOT * MT * 64 * 16);   // 20.4 MiB

    build_afrag<<<(KGTOT * MT * 64 + 255) / 256, 256, 0, stream>>>(down_w, fc_w, afrag);
    conv_mfma<<<dim3(NCHUNK, NB), 256, 0, stream>>>(x, afrag, part);
    finish<<<NB, 256, 0, stream>>>(part, down_b, fc_b, out);
}